// Round 8
// baseline (594.694 us; speedup 1.0000x reference)
//
#include <hip/hip_runtime.h>
#include <math.h>

#define NB 8
#define CIN 512
#define CM 32
#define MG 8
#define HH 128
#define WW 128
#define HWSZ (HH*WW)
#define EPSF 1e-5f
#define COT_ITAU 1.25f   // 1/0.8
#define LAM 0.7f
#define GFLOOR 0.05f

typedef float vf4 __attribute__((ext_vector_type(4)));

__device__ __forceinline__ float wsum(float v){
#pragma unroll
  for (int o = 32; o; o >>= 1) v += __shfl_xor(v, o, 64);
  return v;
}

// transpose compress weights [32][512] -> [512][32]
__global__ void k_tw(const float* __restrict__ w, float* __restrict__ wT){
  int i = blockIdx.x*256 + threadIdx.x;
  if (i < CM*CIN){
    int c = i >> 9, k = i & (CIN-1);
    wT[k*CM + c] = w[i];
  }
}

// compress conv (512->32): split-K within block. 1024 blocks x 256 thr.
// threads 0-127: channels 0-255 for 128 positions; threads 128-255: channels 256-511.
// LDS combine, then first 2 waves store y + stats. 16 waves/CU.
__global__ __launch_bounds__(256) void k_compress(
    const float* __restrict__ x, const float* __restrict__ wT,
    float* __restrict__ y, float* __restrict__ s1, float* __restrict__ s2)
{
  __shared__ float comb[CM][128];
  int tid = threadIdx.x;
  int lp  = tid & 127;
  int kh  = tid >> 7;
  int pos = blockIdx.x*128 + lp;
  int b   = pos >> 14;
  int pp  = pos & (HWSZ-1);
  const float* xb = x + ((size_t)b*CIN + kh*256)*HWSZ + pp;
  const float* wh = wT + kh*256*CM;
  float acc[CM];
#pragma unroll
  for (int c=0;c<CM;c++) acc[c]=0.f;
  float xv[8], xn[8];
#pragma unroll
  for (int u=0;u<8;u++) xv[u] = __builtin_nontemporal_load(&xb[(size_t)u*HWSZ]);
  for (int i=0;i<256;i+=8){
    if (i+8<256){
#pragma unroll
      for (int u=0;u<8;u++) xn[u] = __builtin_nontemporal_load(&xb[(size_t)(i+8+u)*HWSZ]);
    }
#pragma unroll
    for (int u=0;u<8;u++){
      const float* wr = wh + (i+u)*CM;   // uniform -> scalar loads
#pragma unroll
      for (int c=0;c<CM;c++) acc[c]=fmaf(wr[c],xv[u],acc[c]);
    }
#pragma unroll
    for (int u=0;u<8;u++) xv[u]=xn[u];
  }
  if (kh){
#pragma unroll
    for (int c=0;c<CM;c++) comb[c][lp]=acc[c];
  }
  __syncthreads();
  if (!kh){
#pragma unroll
    for (int c=0;c<CM;c++) acc[c]+=comb[c][lp];
    float* yb = y + ((size_t)b*CM)*HWSZ + pp;
#pragma unroll
    for (int c=0;c<CM;c++) yb[(size_t)c*HWSZ]=acc[c];
    float ms=0.f, mq=0.f;
#pragma unroll
    for (int c=0;c<CM;c++){
      float s = wsum(acc[c]);
      float q = wsum(acc[c]*acc[c]);
      if ((tid&63)==c){ ms=s; mq=q; }
    }
    int lane = tid & 63;
    if (lane < CM){
      atomicAdd(&s1[b*CM+lane], ms);
      atomicAdd(&s2[b*CM+lane], mq);
    }
  }
}

// both pools, one pass: grid (bc=256, rowgroup=4); inline affine from raw sums
__global__ __launch_bounds__(256) void k_pools(const float* __restrict__ y,
    const float* __restrict__ s1, const float* __restrict__ s2,
    const float* __restrict__ incg, const float* __restrict__ incb,
    float* __restrict__ hpool, float* __restrict__ wpool)
{
  __shared__ float colacc[WW];
  int bc = blockIdx.x;
  int rg = blockIdx.y;
  int tid = threadIdx.x;
  int c = bc & (CM-1);
  float mu  = s1[bc]*(1.f/HWSZ);
  float var = fmaf(-mu,mu, s2[bc]*(1.f/HWSZ));
  float a   = rsqrtf(var+EPSF)*incg[c];
  float bb  = incb[c]-mu*a;
  if (tid<WW) colacc[tid]=0.f;
  __syncthreads();
  const float4* yp = (const float4*)(y + (size_t)bc*HWSZ + (size_t)rg*32*WW);
  int col4 = tid & 31;
  float c0=0.f,c1=0.f,c2=0.f,c3=0.f;
#pragma unroll
  for (int it=0; it<4; ++it){
    int row = (tid>>5) + it*8;          // 0..31 within group
    float4 t = yp[row*32 + col4];
    float v0=fmaxf(0.f,fmaf(t.x,a,bb)), v1=fmaxf(0.f,fmaf(t.y,a,bb));
    float v2=fmaxf(0.f,fmaf(t.z,a,bb)), v3=fmaxf(0.f,fmaf(t.w,a,bb));
    c0+=v0; c1+=v1; c2+=v2; c3+=v3;
    float rs = v0+v1+v2+v3;
#pragma unroll
    for (int o=16;o;o>>=1) rs += __shfl_xor(rs,o,64);  // 32-lane half = one row
    if ((tid&31)==0) hpool[bc*HH + rg*32 + row] = rs*(1.0f/WW);
  }
  int cb = col4*4;
  atomicAdd(&colacc[cb+0],c0); atomicAdd(&colacc[cb+1],c1);
  atomicAdd(&colacc[cb+2],c2); atomicAdd(&colacc[cb+3],c3);
  __syncthreads();
  if (tid<WW) atomicAdd(&wpool[bc*WW+tid], colacc[tid]*(1.0f/HH));
}

// att_pre statistics only (no store) — at recomputed later
__global__ __launch_bounds__(256) void k_attstat(
  const float* __restrict__ y,
  const float* __restrict__ s1i, const float* __restrict__ s2i,
  const float* __restrict__ incg, const float* __restrict__ incb,
  const float* __restrict__ kw, const float* __restrict__ a1w,
  float* __restrict__ s1, float* __restrict__ s2)
{
  __shared__ float nA[CM], nB[CM];
  int tid=threadIdx.x;
  int b = blockIdx.x >> 6;
  int p = ((blockIdx.x&63)<<8)+tid;
  if (tid<CM){
    float mu  = s1i[b*CM+tid]*(1.f/HWSZ);
    float var = fmaf(-mu,mu, s2i[b*CM+tid]*(1.f/HWSZ));
    float a   = rsqrtf(var+EPSF)*incg[tid];
    nA[tid]=a; nB[tid]=incb[tid]-mu*a;
  }
  __syncthreads();
  size_t base = ((size_t)b*CM)*HWSZ + p;
  float xc[CM], k1[CM], at[CM];
#pragma unroll
  for (int c=0;c<CM;c++)
    xc[c] = fmaxf(0.f, fmaf(y[base+(size_t)c*HWSZ], nA[c], nB[c]));
#pragma unroll
  for (int gI=0;gI<4;gI++)
#pragma unroll
    for (int o=0;o<MG;o++){
      float sk=0.f;
#pragma unroll
      for (int i=0;i<MG;i++) sk = fmaf(kw[gI*64+o*8+i], xc[gI*MG+i], sk);
      k1[gI*MG+o]=sk;
    }
#pragma unroll
  for (int gI=0;gI<4;gI++)
#pragma unroll
    for (int o=0;o<MG;o++){
      float s=0.f;
#pragma unroll
      for (int i=0;i<16;i++){
        float inp = (gI<2) ? k1[gI*16+i] : xc[(gI-2)*16+i];
        s = fmaf(a1w[gI*128+o*16+i], inp, s);
      }
      at[gI*MG+o]=s;
    }
  float ms=0.f,mq=0.f;
#pragma unroll
  for (int c=0;c<CM;c++){
    float s=wsum(at[c]); float q=wsum(at[c]*at[c]);
    if ((tid&63)==c){ms=s;mq=q;}
  }
  int lane=tid&63;
  if (lane<CM){ atomicAdd(&s1[b*CM+lane],ms); atomicAdd(&s2[b*CM+lane],mq); }
}

// softmax denominator (recomputes att from y); blocks 0..15 also run coord MLP
__global__ __launch_bounds__(256) void k_cot2(
  const float* __restrict__ y,
  const float* __restrict__ s1i, const float* __restrict__ s2i,
  const float* __restrict__ incg, const float* __restrict__ incb,
  const float* __restrict__ s1a, const float* __restrict__ s2a,
  const float* __restrict__ ag, const float* __restrict__ ab,
  const float* __restrict__ kw, const float* __restrict__ a1w, const float* __restrict__ a2w,
  const float* __restrict__ hpool, const float* __restrict__ wpool,
  const float* __restrict__ pjw, const float* __restrict__ pjg, const float* __restrict__ pjb,
  const float* __restrict__ chw, const float* __restrict__ chb,
  const float* __restrict__ cww, const float* __restrict__ cwb,
  float* __restrict__ es, float* __restrict__ ah, float* __restrict__ aw)
{
  __shared__ float T[CM][HH+1];
  __shared__ float sa[CM], sb[CM], smx[CM], ssc[CM];
  __shared__ float nA[CM], nB[CM], tA[CM], tB[CM];
  int tid=threadIdx.x;
  int blk=blockIdx.x;
  int b = blk >> 6;
  int p = ((blk&63)<<8)+tid;
  if (tid<CM){
    float mu  = s1i[b*CM+tid]*(1.f/HWSZ);
    float var = fmaf(-mu,mu, s2i[b*CM+tid]*(1.f/HWSZ));
    float a   = rsqrtf(var+EPSF)*incg[tid];
    nA[tid]=a; nB[tid]=incb[tid]-mu*a;
    float mu2  = s1a[b*CM+tid]*(1.f/HWSZ);
    float var2 = fmaf(-mu2,mu2, s2a[b*CM+tid]*(1.f/HWSZ));
    float a2   = rsqrtf(var2+EPSF)*ag[tid];
    tA[tid]=a2; tB[tid]=ab[tid]-mu2*a2;
  }
  __syncthreads();
  size_t base = ((size_t)b*CM)*HWSZ + p;
  float xc[CM], k1[CM], at[CM], l[CM];
#pragma unroll
  for (int c=0;c<CM;c++)
    xc[c] = fmaxf(0.f, fmaf(y[base+(size_t)c*HWSZ], nA[c], nB[c]));
#pragma unroll
  for (int gI=0;gI<4;gI++)
#pragma unroll
    for (int o=0;o<MG;o++){
      float sk=0.f;
#pragma unroll
      for (int i=0;i<MG;i++) sk = fmaf(kw[gI*64+o*8+i], xc[gI*MG+i], sk);
      k1[gI*MG+o]=sk;
    }
#pragma unroll
  for (int gI=0;gI<4;gI++)
#pragma unroll
    for (int o=0;o<MG;o++){
      float s=0.f;
#pragma unroll
      for (int i=0;i<16;i++){
        float inp = (gI<2) ? k1[gI*16+i] : xc[(gI-2)*16+i];
        s = fmaf(a1w[gI*128+o*16+i], inp, s);
      }
      at[gI*MG+o]=s;
    }
#pragma unroll
  for (int c=0;c<CM;c++)
    at[c] = fmaxf(0.f, fmaf(at[c], tA[c], tB[c]));
#pragma unroll
  for (int gI=0;gI<4;gI++)
#pragma unroll
    for (int o=0;o<MG;o++){
      float s=0.f;
#pragma unroll
      for (int i=0;i<MG;i++) s = fmaf(a2w[gI*64+o*8+i], at[gI*8+i], s);
      l[gI*MG+o]=s;
    }
  float ms=0.f;
#pragma unroll
  for (int c=0;c<CM;c++){
    float s = wsum(__expf(l[c]*COT_ITAU));
    if ((tid&63)==c) ms=s;
  }
  int lane=tid&63;
  if (lane<CM) atomicAdd(&es[b*CM+lane], ms);

  // ---- coord MLP (blocks 0..15) ----
  if (blk < 2*NB){
    int bb = blk>>1, path = blk&1;
    const float* pool = path ? wpool : hpool;
    const float* w2   = path ? cww : chw;
    const float* b2   = path ? cwb : chb;
    float* outp       = path ? aw  : ah;
    float z[CM];
    if (tid<HH){
      float in[CM];
#pragma unroll
      for (int c=0;c<CM;c++) in[c] = pool[(bb*CM+c)*HH + tid];
#pragma unroll
      for (int gI=0;gI<4;gI++)
#pragma unroll
        for (int o=0;o<MG;o++){
          float s=0.f;
#pragma unroll
          for (int i=0;i<MG;i++) s = fmaf(pjw[gI*64+o*8+i], in[gI*8+i], s);
          T[gI*8+o][tid] = s;
        }
    }
    __syncthreads();
    if (tid < CM){
      float s=0.f, q=0.f;
      for (int k=0;k<HH;k++){ float t=T[tid][k]; s+=t; q+=t*t; }
      float mu = s*(1.0f/HH);
      float var = q*(1.0f/HH) - mu*mu;
      float a = rsqrtf(var+EPSF)*pjg[tid];
      sa[tid]=a; sb[tid]=pjb[tid]-mu*a;
    }
    __syncthreads();
    if (tid<HH){
      float sil[CM];
#pragma unroll
      for (int c=0;c<CM;c++){
        float val = fmaf(T[c][tid], sa[c], sb[c]);
        sil[c] = val/(1.f+__expf(-val));
      }
#pragma unroll
      for (int gI=0;gI<4;gI++)
#pragma unroll
        for (int o=0;o<MG;o++){
          float s=b2[gI*8+o];
#pragma unroll
          for (int i=0;i<MG;i++) s = fmaf(w2[gI*64+o*8+i], sil[gI*8+i], s);
          z[gI*8+o]=s;
        }
    }
    __syncthreads();
    if (tid<HH){
#pragma unroll
      for (int c=0;c<CM;c++) T[c][tid]=z[c];
    }
    __syncthreads();
    if (tid < CM){
      float mx=-1e30f;
      for (int k=0;k<HH;k++) mx = fmaxf(mx, T[tid][k]);
      float s=0.f;
      for (int k=0;k<HH;k++) s += __expf(T[tid][k]-mx);
      smx[tid]=mx; ssc[tid]=(float)HH/s;
    }
    __syncthreads();
    if (tid<HH){
#pragma unroll
      for (int c=0;c<CM;c++)
        outp[(bb*CM+c)*HH + tid] = __expf(T[c][tid]-smx[c])*ssc[c];
    }
  }
}

// recompute k1/v/att/logits; mix + cot_fuse + coord combine + fusion (+ fus stats)
__global__ __launch_bounds__(256) void k_mix_fuse(
  const float* __restrict__ y,
  const float* __restrict__ s1i, const float* __restrict__ s2i,
  const float* __restrict__ incg, const float* __restrict__ incb,
  const float* __restrict__ s1a, const float* __restrict__ s2a,
  const float* __restrict__ ag, const float* __restrict__ ab,
  const float* __restrict__ kw, const float* __restrict__ vw,
  const float* __restrict__ a1w, const float* __restrict__ a2w,
  const float* __restrict__ ah, const float* __restrict__ awp, const float* __restrict__ es,
  const float* __restrict__ alpha, const float* __restrict__ beta,
  const float* __restrict__ fw, const float* __restrict__ fuw,
  float* __restrict__ fpo, float* __restrict__ s1, float* __restrict__ s2)
{
  __shared__ float nA[CM], nB[CM], tA[CM], tB[CM];
  int tid=threadIdx.x;
  int b = blockIdx.x>>6;
  int p = ((blockIdx.x&63)<<8)+tid;
  int h = p >> 7, w = p & (WW-1);
  if (tid<CM){
    float mu  = s1i[b*CM+tid]*(1.f/HWSZ);
    float var = fmaf(-mu,mu, s2i[b*CM+tid]*(1.f/HWSZ));
    float a   = rsqrtf(var+EPSF)*incg[tid];
    nA[tid]=a; nB[tid]=incb[tid]-mu*a;
    float mu2  = s1a[b*CM+tid]*(1.f/HWSZ);
    float var2 = fmaf(-mu2,mu2, s2a[b*CM+tid]*(1.f/HWSZ));
    float a2   = rsqrtf(var2+EPSF)*ag[tid];
    tA[tid]=a2; tB[tid]=ab[tid]-mu2*a2;
  }
  __syncthreads();
  size_t base = ((size_t)b*CM)*HWSZ + p;
  float al=alpha[0], be=beta[0];
  float xc[CM], k1[CM], at[CM], l[CM], t[CM];
#pragma unroll
  for (int c=0;c<CM;c++)
    xc[c] = fmaxf(0.f, fmaf(y[base+(size_t)c*HWSZ], nA[c], nB[c]));
#pragma unroll
  for (int gI=0;gI<4;gI++)
#pragma unroll
    for (int o=0;o<MG;o++){
      float sk=0.f;
#pragma unroll
      for (int i=0;i<MG;i++) sk = fmaf(kw[gI*64+o*8+i], xc[gI*MG+i], sk);
      k1[gI*MG+o]=sk;
    }
#pragma unroll
  for (int gI=0;gI<4;gI++)
#pragma unroll
    for (int o=0;o<MG;o++){
      float s=0.f;
#pragma unroll
      for (int i=0;i<16;i++){
        float inp = (gI<2) ? k1[gI*16+i] : xc[(gI-2)*16+i];
        s = fmaf(a1w[gI*128+o*16+i], inp, s);
      }
      at[gI*MG+o]=s;
    }
#pragma unroll
  for (int c=0;c<CM;c++)
    at[c] = fmaxf(0.f, fmaf(at[c], tA[c], tB[c]));
#pragma unroll
  for (int gI=0;gI<4;gI++)
#pragma unroll
    for (int o=0;o<MG;o++){
      float s=0.f;
#pragma unroll
      for (int i=0;i<MG;i++) s = fmaf(a2w[gI*64+o*8+i], at[gI*8+i], s);
      l[gI*MG+o]=s;
    }
#pragma unroll
  for (int gI=0;gI<4;gI++)
#pragma unroll
    for (int o=0;o<MG;o++){
      float sv=0.f;
#pragma unroll
      for (int i=0;i<MG;i++) sv = fmaf(vw[gI*64+o*8+i], xc[gI*MG+i], sv);
      int c = gI*MG+o;
      float lgv = l[c];
      float sm = __expf(lgv*COT_ITAU) * (16384.f/es[b*CM+c]);
      float sg = 1.f/(1.f+__expf(-lgv));
      float mix = (1.f-LAM)*sg + LAM*sm;
      t[c] = fmaf(mix, sv, k1[c]);
    }
  float co[CM];
#pragma unroll
  for (int c=0;c<CM;c++){
    float wl = al*ah[(b*CM+c)*HH + h] + be*awp[(b*CM+c)*WW + w];
    co[c] = xc[c] * wl;   // kappa = 1
  }
  float cot[CM];
#pragma unroll
  for (int o=0;o<CM;o++){
    float s=0.f;
#pragma unroll
    for (int i=0;i<CM;i++) s = fmaf(fw[o*CM+i], t[i], s);
    cot[o]=s;
  }
  float ms=0.f, mq=0.f;
#pragma unroll
  for (int o=0;o<CM;o++){
    float s=0.f;
#pragma unroll
    for (int i=0;i<CM;i++) s = fmaf(fuw[o*64+i], co[i], s);
#pragma unroll
    for (int i=0;i<CM;i++) s = fmaf(fuw[o*64+32+i], cot[i], s);
    fpo[base+(size_t)o*HWSZ]=s;
    float ss = wsum(s); float qq = wsum(s*s);
    if ((tid&63)==o){ ms=ss; mq=qq; }
  }
  int lane=tid&63;
  if (lane<CM){ atomicAdd(&s1[b*CM+lane],ms); atomicAdd(&s2[b*CM+lane],mq); }
}

// gate statistics: sum of relu(norm(fused_pre)) per (b,c), inline affine
__global__ __launch_bounds__(256) void k_gstat(const float4* __restrict__ fp,
  const float* __restrict__ s1f, const float* __restrict__ s2f,
  const float* __restrict__ fg, const float* __restrict__ fb,
  float* __restrict__ gsum)
{
  int idx = blockIdx.x*256+threadIdx.x;  // NB*CM*HWSZ/4
  int bc = idx >> 12;
  int c = bc & (CM-1);
  float mu  = s1f[bc]*(1.f/HWSZ);
  float var = fmaf(-mu,mu, s2f[bc]*(1.f/HWSZ));
  float a   = rsqrtf(var+EPSF)*fg[c];
  float bb  = fb[c]-mu*a;
  float4 tv = fp[idx];
  float s = fmaxf(0.f,fmaf(tv.x,a,bb))+fmaxf(0.f,fmaf(tv.y,a,bb))
          + fmaxf(0.f,fmaf(tv.z,a,bb))+fmaxf(0.f,fmaf(tv.w,a,bb));
  s = wsum(s);
  if ((threadIdx.x&63)==0) atomicAdd(&gsum[bc], s);
}

// expand conv 32->512: inline fus affine + inline gate; nt stores
__global__ __launch_bounds__(256) void k_expand(const float4* __restrict__ fp4,
  const float* __restrict__ s1f, const float* __restrict__ s2f,
  const float* __restrict__ fg, const float* __restrict__ fb,
  const float* __restrict__ gw, const float* __restrict__ gsum,
  const float* __restrict__ ew, vf4* __restrict__ out4)
{
  __shared__ float fA[CM], fB[CM];
  int tid = threadIdx.x;
  int b = blockIdx.x >> 4;
  int tile = blockIdx.x & 15;
  int p4 = tile*256 + tid;            // float4 idx within batch plane (0..4095)
  int og = blockIdx.y * 64;
  if (tid<CM){
    float mu  = s1f[b*CM+tid]*(1.f/HWSZ);
    float var = fmaf(-mu,mu, s2f[b*CM+tid]*(1.f/HWSZ));
    float a   = rsqrtf(var+EPSF)*fg[tid];
    fA[tid]=a; fB[tid]=fb[tid]-mu*a;
  }
  float s=0.f;
#pragma unroll
  for (int c=0;c<CM;c++) s = fmaf(gw[c], gsum[b*CM+c], s);
  s *= (1.0f/HWSZ);
  float gt = 1.f/(1.f+__expf(-s));
  float sc = gt*(1.f-GFLOOR)+GFLOOR;
  __syncthreads();
  float4 f[CM];
  const float4* fbp = fp4 + ((size_t)b*CM)*(HWSZ/4) + p4;
#pragma unroll
  for (int c=0;c<CM;c++){
    float4 t = fbp[(size_t)c*(HWSZ/4)];
    float a=fA[c], bb=fB[c];
    f[c].x = fmaxf(0.f, fmaf(t.x,a,bb))*sc;
    f[c].y = fmaxf(0.f, fmaf(t.y,a,bb))*sc;
    f[c].z = fmaxf(0.f, fmaf(t.z,a,bb))*sc;
    f[c].w = fmaxf(0.f, fmaf(t.w,a,bb))*sc;
  }
  vf4* ob = out4 + ((size_t)b*CIN + og)*(HWSZ/4) + p4;
  for (int j=0;j<64;j++){
    const float* wr = ew + (og+j)*CM;   // uniform -> scalar loads
    vf4 acc = (vf4)(0.f);
#pragma unroll
    for (int c=0;c<CM;c++){
      float wv = wr[c];
      acc.x = fmaf(wv, f[c].x, acc.x);
      acc.y = fmaf(wv, f[c].y, acc.y);
      acc.z = fmaf(wv, f[c].z, acc.z);
      acc.w = fmaf(wv, f[c].w, acc.w);
    }
    __builtin_nontemporal_store(acc, &ob[(size_t)j*(HWSZ/4)]);
  }
}

extern "C" void kernel_launch(void* const* d_in, const int* in_sizes, int n_in,
                              void* d_out, int out_size, void* d_ws, size_t ws_size,
                              hipStream_t stream)
{
  const float* x    = (const float*)d_in[0];
  const float* cw   = (const float*)d_in[1];
  const float* incg = (const float*)d_in[2];
  const float* incb = (const float*)d_in[3];
  const float* pjw  = (const float*)d_in[4];
  const float* pjg  = (const float*)d_in[5];
  const float* pjb  = (const float*)d_in[6];
  const float* chw  = (const float*)d_in[7];
  const float* chb  = (const float*)d_in[8];
  const float* cww  = (const float*)d_in[9];
  const float* cwb  = (const float*)d_in[10];
  const float* alpha= (const float*)d_in[11];
  const float* beta = (const float*)d_in[12];
  const float* kw   = (const float*)d_in[13];
  const float* vw   = (const float*)d_in[14];
  const float* a1w  = (const float*)d_in[15];
  const float* ag   = (const float*)d_in[16];
  const float* ab   = (const float*)d_in[17];
  const float* a2w  = (const float*)d_in[18];
  const float* fw   = (const float*)d_in[19];
  const float* fuw  = (const float*)d_in[20];
  const float* fg   = (const float*)d_in[21];
  const float* fb   = (const float*)d_in[22];
  const float* gw   = (const float*)d_in[23];
  const float* ew   = (const float*)d_in[24];
  float* out = (float*)d_out;

  float* ws = (float*)d_ws;
  const size_t BIG = (size_t)NB*CM*HWSZ;  // 4,194,304 floats (16 MiB)
  float* y    = ws;            // compressed pre-norm
  float* F    = ws +   BIG;    // fused_pre
  float* sm   = ws + 2*BIG;
  float* acc   = sm;  sm += 2048;            // zeroed accumulators
  float* statS = acc,      *statQ = acc+256;
  float* attS  = acc+512,  *attQ  = acc+768;
  float* esum  = acc+1024;
  float* fusS  = acc+1280, *fusQ  = acc+1536;
  float* gsum  = acc+1792;
  float* wpool = sm;  sm += NB*CM*WW;        // zeroed (atomic-accumulated)
  float* wT    = sm;  sm += CM*CIN;
  float* hpool = sm;  sm += NB*CM*HH;        // direct-written
  float* ahB   = sm;  sm += NB*CM*HH;
  float* awB   = sm;  sm += NB*CM*WW;

  hipMemsetAsync(acc, 0, (2048 + NB*CM*WW)*sizeof(float), stream);
  k_tw<<<64,256,0,stream>>>(cw, wT);
  k_compress<<<1024,256,0,stream>>>(x, wT, y, statS, statQ);
  k_pools<<<dim3(NB*CM,4),256,0,stream>>>(y,statS,statQ,incg,incb,hpool,wpool);
  k_attstat<<<512,256,0,stream>>>(y,statS,statQ,incg,incb,kw,a1w,attS,attQ);
  k_cot2<<<512,256,0,stream>>>(y,statS,statQ,incg,incb,attS,attQ,ag,ab,kw,a1w,a2w,
                               hpool,wpool,pjw,pjg,pjb,chw,chb,cww,cwb,esum,ahB,awB);
  k_mix_fuse<<<512,256,0,stream>>>(y,statS,statQ,incg,incb,attS,attQ,ag,ab,kw,vw,a1w,a2w,
                                   ahB,awB,esum,alpha,beta,fw,fuw,F,fusS,fusQ);
  k_gstat<<<4096,256,0,stream>>>((const float4*)F,fusS,fusQ,fg,fb,gsum);
  k_expand<<<dim3(128,8),256,0,stream>>>((const float4*)F,fusS,fusQ,fg,fb,gw,gsum,ew,(vf4*)out);
}

// Round 9
// 397.645 us; speedup vs baseline: 1.4955x; 1.4955x over previous
//
#include <hip/hip_runtime.h>
#include <math.h>

#define NB 8
#define CIN 512
#define CM 32
#define MG 8
#define HH 128
#define WW 128
#define HWSZ (HH*WW)
#define EPSF 1e-5f
#define COT_ITAU 1.25f   // 1/0.8
#define LAM 0.7f
#define GFLOOR 0.05f

typedef float vf4 __attribute__((ext_vector_type(4)));

__device__ __forceinline__ float wsum(float v){
#pragma unroll
  for (int o = 32; o; o >>= 1) v += __shfl_xor(v, o, 64);
  return v;
}

// transpose compress weights [32][512] -> [512][32]
__global__ void k_tw(const float* __restrict__ w, float* __restrict__ wT){
  int i = blockIdx.x*256 + threadIdx.x;
  if (i < CM*CIN){
    int c = i >> 9, k = i & (CIN-1);
    wT[k*CM + c] = w[i];
  }
}

// compress conv (512->32): round-7-exact structure (512 blocks, 8-deep, nt loads)
__global__ __launch_bounds__(256) void k_compress(
    const float* __restrict__ x, const float* __restrict__ wT,
    float* __restrict__ y, float* __restrict__ s1, float* __restrict__ s2)
{
  int tid = threadIdx.x;
  int b = blockIdx.x >> 6;
  int p = ((blockIdx.x & 63) << 8) + tid;
  const float* xb = x + ((size_t)b*CIN)*HWSZ + p;
  float acc[CM];
#pragma unroll
  for (int c=0;c<CM;c++) acc[c]=0.f;
  float xv[8], xn[8];
#pragma unroll
  for (int u=0;u<8;u++) xv[u] = __builtin_nontemporal_load(&xb[(size_t)u*HWSZ]);
  for (int i=0;i<CIN;i+=8){
    if (i+8<CIN){
#pragma unroll
      for (int u=0;u<8;u++) xn[u] = __builtin_nontemporal_load(&xb[(size_t)(i+8+u)*HWSZ]);
    }
#pragma unroll
    for (int u=0;u<8;u++){
      const float* wr = wT + (i+u)*CM;   // uniform -> scalar loads
#pragma unroll
      for (int c=0;c<CM;c++) acc[c]=fmaf(wr[c],xv[u],acc[c]);
    }
#pragma unroll
    for (int u=0;u<8;u++) xv[u]=xn[u];
  }
  float* yb = y + ((size_t)b*CM)*HWSZ + p;
#pragma unroll
  for (int c=0;c<CM;c++) yb[(size_t)c*HWSZ] = acc[c];
  float ms=0.f, mq=0.f;
#pragma unroll
  for (int c=0;c<CM;c++){
    float s = wsum(acc[c]);
    float q = wsum(acc[c]*acc[c]);
    if ((tid&63)==c){ ms=s; mq=q; }
  }
  int lane = tid & 63;
  if (lane < CM){
    atomicAdd(&s1[b*CM+lane], ms);
    atomicAdd(&s2[b*CM+lane], mq);
  }
}

// att_pre stats + BOTH pools in one y-pass.
// Block = 256 positions (2 rows). hpool: wave wsum + atomics (zeroed).
// wpool: LDS row-pair combine -> per-block partials wpart[blk][CM][WW].
__global__ __launch_bounds__(256) void k_poolstat(
  const float* __restrict__ y,
  const float* __restrict__ s1i, const float* __restrict__ s2i,
  const float* __restrict__ incg, const float* __restrict__ incb,
  const float* __restrict__ kw, const float* __restrict__ a1w,
  float* __restrict__ s1, float* __restrict__ s2,
  float* __restrict__ hpool, float* __restrict__ wpart)
{
  __shared__ float nA[CM], nB[CM];
  __shared__ float sh[CM][128];
  int tid=threadIdx.x;
  int blk=blockIdx.x;
  int b = blk >> 6;
  int p = ((blk&63)<<8)+tid;
  if (tid<CM){
    float mu  = s1i[b*CM+tid]*(1.f/HWSZ);
    float var = fmaf(-mu,mu, s2i[b*CM+tid]*(1.f/HWSZ));
    float a   = rsqrtf(var+EPSF)*incg[tid];
    nA[tid]=a; nB[tid]=incb[tid]-mu*a;
  }
  __syncthreads();
  size_t base = ((size_t)b*CM)*HWSZ + p;
  float xc[CM], k1[CM], at[CM];
#pragma unroll
  for (int c=0;c<CM;c++)
    xc[c] = fmaxf(0.f, fmaf(y[base+(size_t)c*HWSZ], nA[c], nB[c]));
  // ---- wpool partial: row0 + row1 per column ----
  if (tid>=128){
#pragma unroll
    for (int c=0;c<CM;c++) sh[c][tid-128]=xc[c];
  }
  __syncthreads();
  if (tid<128){
    float* wp = wpart + (size_t)blk*(CM*WW) + tid;
#pragma unroll
    for (int c=0;c<CM;c++) wp[c*WW] = xc[c] + sh[c][tid];
  }
  // ---- hpool: per-wave row sums (row uniform within wave) ----
  {
    int hrow = p >> 7;
    float ms=0.f;
#pragma unroll
    for (int c=0;c<CM;c++){
      float s=wsum(xc[c]);
      if ((tid&63)==c) ms=s;
    }
    int lane=tid&63;
    if (lane<CM) atomicAdd(&hpool[(b*CM+lane)*HH+hrow], ms*(1.f/WW));
  }
  // ---- att_pre stats ----
#pragma unroll
  for (int gI=0;gI<4;gI++)
#pragma unroll
    for (int o=0;o<MG;o++){
      float sk=0.f;
#pragma unroll
      for (int i=0;i<MG;i++) sk = fmaf(kw[gI*64+o*8+i], xc[gI*MG+i], sk);
      k1[gI*MG+o]=sk;
    }
#pragma unroll
  for (int gI=0;gI<4;gI++)
#pragma unroll
    for (int o=0;o<MG;o++){
      float s=0.f;
#pragma unroll
      for (int i=0;i<16;i++){
        float inp = (gI<2) ? k1[gI*16+i] : xc[(gI-2)*16+i];
        s = fmaf(a1w[gI*128+o*16+i], inp, s);
      }
      at[gI*MG+o]=s;
    }
  float ms=0.f,mq=0.f;
#pragma unroll
  for (int c=0;c<CM;c++){
    float s=wsum(at[c]); float q=wsum(at[c]*at[c]);
    if ((tid&63)==c){ms=s;mq=q;}
  }
  int lane=tid&63;
  if (lane<CM){ atomicAdd(&s1[b*CM+lane],ms); atomicAdd(&s2[b*CM+lane],mq); }
}

// softmax denominator (recomputes att from y); blocks 0..15 also run coord MLP
// (path==1 blocks first reduce the 64 wpart partials of their batch)
__global__ __launch_bounds__(256) void k_cot2(
  const float* __restrict__ y,
  const float* __restrict__ s1i, const float* __restrict__ s2i,
  const float* __restrict__ incg, const float* __restrict__ incb,
  const float* __restrict__ s1a, const float* __restrict__ s2a,
  const float* __restrict__ ag, const float* __restrict__ ab,
  const float* __restrict__ kw, const float* __restrict__ a1w, const float* __restrict__ a2w,
  const float* __restrict__ hpool, const float* __restrict__ wpart,
  const float* __restrict__ pjw, const float* __restrict__ pjg, const float* __restrict__ pjb,
  const float* __restrict__ chw, const float* __restrict__ chb,
  const float* __restrict__ cww, const float* __restrict__ cwb,
  float* __restrict__ es, float* __restrict__ ah, float* __restrict__ aw)
{
  __shared__ float T[CM][HH+1];
  __shared__ float sa[CM], sb[CM], smx[CM], ssc[CM];
  __shared__ float nA[CM], nB[CM], tA[CM], tB[CM];
  int tid=threadIdx.x;
  int blk=blockIdx.x;
  int b = blk >> 6;
  int p = ((blk&63)<<8)+tid;
  if (tid<CM){
    float mu  = s1i[b*CM+tid]*(1.f/HWSZ);
    float var = fmaf(-mu,mu, s2i[b*CM+tid]*(1.f/HWSZ));
    float a   = rsqrtf(var+EPSF)*incg[tid];
    nA[tid]=a; nB[tid]=incb[tid]-mu*a;
    float mu2  = s1a[b*CM+tid]*(1.f/HWSZ);
    float var2 = fmaf(-mu2,mu2, s2a[b*CM+tid]*(1.f/HWSZ));
    float a2   = rsqrtf(var2+EPSF)*ag[tid];
    tA[tid]=a2; tB[tid]=ab[tid]-mu2*a2;
  }
  __syncthreads();
  size_t base = ((size_t)b*CM)*HWSZ + p;
  float xc[CM], k1[CM], at[CM], l[CM];
#pragma unroll
  for (int c=0;c<CM;c++)
    xc[c] = fmaxf(0.f, fmaf(y[base+(size_t)c*HWSZ], nA[c], nB[c]));
#pragma unroll
  for (int gI=0;gI<4;gI++)
#pragma unroll
    for (int o=0;o<MG;o++){
      float sk=0.f;
#pragma unroll
      for (int i=0;i<MG;i++) sk = fmaf(kw[gI*64+o*8+i], xc[gI*MG+i], sk);
      k1[gI*MG+o]=sk;
    }
#pragma unroll
  for (int gI=0;gI<4;gI++)
#pragma unroll
    for (int o=0;o<MG;o++){
      float s=0.f;
#pragma unroll
      for (int i=0;i<16;i++){
        float inp = (gI<2) ? k1[gI*16+i] : xc[(gI-2)*16+i];
        s = fmaf(a1w[gI*128+o*16+i], inp, s);
      }
      at[gI*MG+o]=s;
    }
#pragma unroll
  for (int c=0;c<CM;c++)
    at[c] = fmaxf(0.f, fmaf(at[c], tA[c], tB[c]));
#pragma unroll
  for (int gI=0;gI<4;gI++)
#pragma unroll
    for (int o=0;o<MG;o++){
      float s=0.f;
#pragma unroll
      for (int i=0;i<MG;i++) s = fmaf(a2w[gI*64+o*8+i], at[gI*8+i], s);
      l[gI*MG+o]=s;
    }
  float ms=0.f;
#pragma unroll
  for (int c=0;c<CM;c++){
    float s = wsum(__expf(l[c]*COT_ITAU));
    if ((tid&63)==c) ms=s;
  }
  int lane=tid&63;
  if (lane<CM) atomicAdd(&es[b*CM+lane], ms);

  // ---- coord MLP (blocks 0..15) ----
  if (blk < 2*NB){
    int bb = blk>>1, path = blk&1;
    const float* w2 = path ? cww : chw;
    const float* b2 = path ? cwb : chb;
    float* outp     = path ? aw  : ah;
    float in[CM];
    if (path==1){
      // reduce this batch's 64 wpart partials -> T[c][col]
      __syncthreads();
      for (int t=tid; t<CM*WW; t+=256){
        const float* src = wpart + (size_t)(bb*64)*(CM*WW) + t;
        float s=0.f;
#pragma unroll 8
        for (int k=0;k<64;k++) s += src[(size_t)k*(CM*WW)];
        T[t>>7][t&127] = s*(1.f/HH);
      }
      __syncthreads();
      if (tid<HH){
#pragma unroll
        for (int c=0;c<CM;c++) in[c]=T[c][tid];
      }
      __syncthreads();
    } else {
      if (tid<HH){
#pragma unroll
        for (int c=0;c<CM;c++) in[c]=hpool[(bb*CM+c)*HH+tid];
      }
      __syncthreads();
    }
    if (tid<HH){
#pragma unroll
      for (int gI=0;gI<4;gI++)
#pragma unroll
        for (int o=0;o<MG;o++){
          float s=0.f;
#pragma unroll
          for (int i=0;i<MG;i++) s = fmaf(pjw[gI*64+o*8+i], in[gI*8+i], s);
          T[gI*8+o][tid] = s;
        }
    }
    __syncthreads();
    if (tid < CM){
      float s=0.f, q=0.f;
      for (int k=0;k<HH;k++){ float t=T[tid][k]; s+=t; q+=t*t; }
      float mu = s*(1.0f/HH);
      float var = q*(1.0f/HH) - mu*mu;
      float a = rsqrtf(var+EPSF)*pjg[tid];
      sa[tid]=a; sb[tid]=pjb[tid]-mu*a;
    }
    __syncthreads();
    float z[CM];
    if (tid<HH){
      float sil[CM];
#pragma unroll
      for (int c=0;c<CM;c++){
        float val = fmaf(T[c][tid], sa[c], sb[c]);
        sil[c] = val/(1.f+__expf(-val));
      }
#pragma unroll
      for (int gI=0;gI<4;gI++)
#pragma unroll
        for (int o=0;o<MG;o++){
          float s=b2[gI*8+o];
#pragma unroll
          for (int i=0;i<MG;i++) s = fmaf(w2[gI*64+o*8+i], sil[gI*8+i], s);
          z[gI*8+o]=s;
        }
    }
    __syncthreads();
    if (tid<HH){
#pragma unroll
      for (int c=0;c<CM;c++) T[c][tid]=z[c];
    }
    __syncthreads();
    if (tid < CM){
      float mx=-1e30f;
      for (int k=0;k<HH;k++) mx = fmaxf(mx, T[tid][k]);
      float s=0.f;
      for (int k=0;k<HH;k++) s += __expf(T[tid][k]-mx);
      smx[tid]=mx; ssc[tid]=(float)HH/s;
    }
    __syncthreads();
    if (tid<HH){
#pragma unroll
      for (int c=0;c<CM;c++)
        outp[(bb*CM+c)*HH + tid] = __expf(T[c][tid]-smx[c])*ssc[c];
    }
  }
}

// recompute k1/v/att/logits; mix + cot_fuse + coord combine + fusion (+ fus stats)
__global__ __launch_bounds__(256) void k_mix_fuse(
  const float* __restrict__ y,
  const float* __restrict__ s1i, const float* __restrict__ s2i,
  const float* __restrict__ incg, const float* __restrict__ incb,
  const float* __restrict__ s1a, const float* __restrict__ s2a,
  const float* __restrict__ ag, const float* __restrict__ ab,
  const float* __restrict__ kw, const float* __restrict__ vw,
  const float* __restrict__ a1w, const float* __restrict__ a2w,
  const float* __restrict__ ah, const float* __restrict__ awp, const float* __restrict__ es,
  const float* __restrict__ alpha, const float* __restrict__ beta,
  const float* __restrict__ fw, const float* __restrict__ fuw,
  float* __restrict__ fpo, float* __restrict__ s1, float* __restrict__ s2)
{
  __shared__ float nA[CM], nB[CM], tA[CM], tB[CM];
  int tid=threadIdx.x;
  int b = blockIdx.x>>6;
  int p = ((blockIdx.x&63)<<8)+tid;
  int h = p >> 7, w = p & (WW-1);
  if (tid<CM){
    float mu  = s1i[b*CM+tid]*(1.f/HWSZ);
    float var = fmaf(-mu,mu, s2i[b*CM+tid]*(1.f/HWSZ));
    float a   = rsqrtf(var+EPSF)*incg[tid];
    nA[tid]=a; nB[tid]=incb[tid]-mu*a;
    float mu2  = s1a[b*CM+tid]*(1.f/HWSZ);
    float var2 = fmaf(-mu2,mu2, s2a[b*CM+tid]*(1.f/HWSZ));
    float a2   = rsqrtf(var2+EPSF)*ag[tid];
    tA[tid]=a2; tB[tid]=ab[tid]-mu2*a2;
  }
  __syncthreads();
  size_t base = ((size_t)b*CM)*HWSZ + p;
  float al=alpha[0], be=beta[0];
  float xc[CM], k1[CM], at[CM], l[CM], t[CM];
#pragma unroll
  for (int c=0;c<CM;c++)
    xc[c] = fmaxf(0.f, fmaf(y[base+(size_t)c*HWSZ], nA[c], nB[c]));
#pragma unroll
  for (int gI=0;gI<4;gI++)
#pragma unroll
    for (int o=0;o<MG;o++){
      float sk=0.f;
#pragma unroll
      for (int i=0;i<MG;i++) sk = fmaf(kw[gI*64+o*8+i], xc[gI*MG+i], sk);
      k1[gI*MG+o]=sk;
    }
#pragma unroll
  for (int gI=0;gI<4;gI++)
#pragma unroll
    for (int o=0;o<MG;o++){
      float s=0.f;
#pragma unroll
      for (int i=0;i<16;i++){
        float inp = (gI<2) ? k1[gI*16+i] : xc[(gI-2)*16+i];
        s = fmaf(a1w[gI*128+o*16+i], inp, s);
      }
      at[gI*MG+o]=s;
    }
#pragma unroll
  for (int c=0;c<CM;c++)
    at[c] = fmaxf(0.f, fmaf(at[c], tA[c], tB[c]));
#pragma unroll
  for (int gI=0;gI<4;gI++)
#pragma unroll
    for (int o=0;o<MG;o++){
      float s=0.f;
#pragma unroll
      for (int i=0;i<MG;i++) s = fmaf(a2w[gI*64+o*8+i], at[gI*8+i], s);
      l[gI*MG+o]=s;
    }
#pragma unroll
  for (int gI=0;gI<4;gI++)
#pragma unroll
    for (int o=0;o<MG;o++){
      float sv=0.f;
#pragma unroll
      for (int i=0;i<MG;i++) sv = fmaf(vw[gI*64+o*8+i], xc[gI*MG+i], sv);
      int c = gI*MG+o;
      float lgv = l[c];
      float sm = __expf(lgv*COT_ITAU) * (16384.f/es[b*CM+c]);
      float sg = 1.f/(1.f+__expf(-lgv));
      float mix = (1.f-LAM)*sg + LAM*sm;
      t[c] = fmaf(mix, sv, k1[c]);
    }
  float co[CM];
#pragma unroll
  for (int c=0;c<CM;c++){
    float wl = al*ah[(b*CM+c)*HH + h] + be*awp[(b*CM+c)*WW + w];
    co[c] = xc[c] * wl;   // kappa = 1
  }
  float cot[CM];
#pragma unroll
  for (int o=0;o<CM;o++){
    float s=0.f;
#pragma unroll
    for (int i=0;i<CM;i++) s = fmaf(fw[o*CM+i], t[i], s);
    cot[o]=s;
  }
  float ms=0.f, mq=0.f;
#pragma unroll
  for (int o=0;o<CM;o++){
    float s=0.f;
#pragma unroll
    for (int i=0;i<CM;i++) s = fmaf(fuw[o*64+i], co[i], s);
#pragma unroll
    for (int i=0;i<CM;i++) s = fmaf(fuw[o*64+32+i], cot[i], s);
    fpo[base+(size_t)o*HWSZ]=s;
    float ss = wsum(s); float qq = wsum(s*s);
    if ((tid&63)==o){ ms=ss; mq=qq; }
  }
  int lane=tid&63;
  if (lane<CM){ atomicAdd(&s1[b*CM+lane],ms); atomicAdd(&s2[b*CM+lane],mq); }
}

// gate statistics: sum of relu(norm(fused_pre)) per (b,c), inline affine
__global__ __launch_bounds__(256) void k_gstat(const float4* __restrict__ fp,
  const float* __restrict__ s1f, const float* __restrict__ s2f,
  const float* __restrict__ fg, const float* __restrict__ fb,
  float* __restrict__ gsum)
{
  int idx = blockIdx.x*256+threadIdx.x;  // NB*CM*HWSZ/4
  int bc = idx >> 12;
  int c = bc & (CM-1);
  float mu  = s1f[bc]*(1.f/HWSZ);
  float var = fmaf(-mu,mu, s2f[bc]*(1.f/HWSZ));
  float a   = rsqrtf(var+EPSF)*fg[c];
  float bb  = fb[c]-mu*a;
  float4 tv = fp[idx];
  float s = fmaxf(0.f,fmaf(tv.x,a,bb))+fmaxf(0.f,fmaf(tv.y,a,bb))
          + fmaxf(0.f,fmaf(tv.z,a,bb))+fmaxf(0.f,fmaf(tv.w,a,bb));
  s = wsum(s);
  if ((threadIdx.x&63)==0) atomicAdd(&gsum[bc], s);
}

// expand conv 32->512: inline fus affine + inline gate; nt stores
__global__ __launch_bounds__(256) void k_expand(const float4* __restrict__ fp4,
  const float* __restrict__ s1f, const float* __restrict__ s2f,
  const float* __restrict__ fg, const float* __restrict__ fb,
  const float* __restrict__ gw, const float* __restrict__ gsum,
  const float* __restrict__ ew, vf4* __restrict__ out4)
{
  __shared__ float fA[CM], fB[CM];
  int tid = threadIdx.x;
  int b = blockIdx.x >> 4;
  int tile = blockIdx.x & 15;
  int p4 = tile*256 + tid;            // float4 idx within batch plane (0..4095)
  int og = blockIdx.y * 64;
  if (tid<CM){
    float mu  = s1f[b*CM+tid]*(1.f/HWSZ);
    float var = fmaf(-mu,mu, s2f[b*CM+tid]*(1.f/HWSZ));
    float a   = rsqrtf(var+EPSF)*fg[tid];
    fA[tid]=a; fB[tid]=fb[tid]-mu*a;
  }
  float s=0.f;
#pragma unroll
  for (int c=0;c<CM;c++) s = fmaf(gw[c], gsum[b*CM+c], s);
  s *= (1.0f/HWSZ);
  float gt = 1.f/(1.f+__expf(-s));
  float sc = gt*(1.f-GFLOOR)+GFLOOR;
  __syncthreads();
  float4 f[CM];
  const float4* fbp = fp4 + ((size_t)b*CM)*(HWSZ/4) + p4;
#pragma unroll
  for (int c=0;c<CM;c++){
    float4 t = fbp[(size_t)c*(HWSZ/4)];
    float a=fA[c], bb=fB[c];
    f[c].x = fmaxf(0.f, fmaf(t.x,a,bb))*sc;
    f[c].y = fmaxf(0.f, fmaf(t.y,a,bb))*sc;
    f[c].z = fmaxf(0.f, fmaf(t.z,a,bb))*sc;
    f[c].w = fmaxf(0.f, fmaf(t.w,a,bb))*sc;
  }
  vf4* ob = out4 + ((size_t)b*CIN + og)*(HWSZ/4) + p4;
  for (int j=0;j<64;j++){
    const float* wr = ew + (og+j)*CM;   // uniform -> scalar loads
    vf4 acc = (vf4)(0.f);
#pragma unroll
    for (int c=0;c<CM;c++){
      float wv = wr[c];
      acc.x = fmaf(wv, f[c].x, acc.x);
      acc.y = fmaf(wv, f[c].y, acc.y);
      acc.z = fmaf(wv, f[c].z, acc.z);
      acc.w = fmaf(wv, f[c].w, acc.w);
    }
    __builtin_nontemporal_store(acc, &ob[(size_t)j*(HWSZ/4)]);
  }
}

extern "C" void kernel_launch(void* const* d_in, const int* in_sizes, int n_in,
                              void* d_out, int out_size, void* d_ws, size_t ws_size,
                              hipStream_t stream)
{
  const float* x    = (const float*)d_in[0];
  const float* cw   = (const float*)d_in[1];
  const float* incg = (const float*)d_in[2];
  const float* incb = (const float*)d_in[3];
  const float* pjw  = (const float*)d_in[4];
  const float* pjg  = (const float*)d_in[5];
  const float* pjb  = (const float*)d_in[6];
  const float* chw  = (const float*)d_in[7];
  const float* chb  = (const float*)d_in[8];
  const float* cww  = (const float*)d_in[9];
  const float* cwb  = (const float*)d_in[10];
  const float* alpha= (const float*)d_in[11];
  const float* beta = (const float*)d_in[12];
  const float* kw   = (const float*)d_in[13];
  const float* vw   = (const float*)d_in[14];
  const float* a1w  = (const float*)d_in[15];
  const float* ag   = (const float*)d_in[16];
  const float* ab   = (const float*)d_in[17];
  const float* a2w  = (const float*)d_in[18];
  const float* fw   = (const float*)d_in[19];
  const float* fuw  = (const float*)d_in[20];
  const float* fg   = (const float*)d_in[21];
  const float* fb   = (const float*)d_in[22];
  const float* gw   = (const float*)d_in[23];
  const float* ew   = (const float*)d_in[24];
  float* out = (float*)d_out;

  float* ws = (float*)d_ws;
  const size_t BIG = (size_t)NB*CM*HWSZ;  // 4,194,304 floats (16 MiB)
  float* y    = ws;            // compressed pre-norm
  float* F    = ws +   BIG;    // fused_pre
  float* sm   = ws + 2*BIG;
  // zeroed region: acc (2048) + hpool (NB*CM*HH)
  float* acc   = sm;  sm += 2048;
  float* statS = acc,      *statQ = acc+256;
  float* attS  = acc+512,  *attQ  = acc+768;
  float* esum  = acc+1024;
  float* fusS  = acc+1280, *fusQ  = acc+1536;
  float* gsum  = acc+1792;
  float* hpool = sm;  sm += NB*CM*HH;        // atomic-accumulated
  float* wT    = sm;  sm += CM*CIN;
  float* wpart = sm;  sm += (size_t)512*CM*WW;  // 8 MiB partials
  float* ahB   = sm;  sm += NB*CM*HH;
  float* awB   = sm;  sm += NB*CM*WW;

  hipMemsetAsync(acc, 0, (2048 + NB*CM*HH)*sizeof(float), stream);
  k_tw<<<64,256,0,stream>>>(cw, wT);
  k_compress<<<512,256,0,stream>>>(x, wT, y, statS, statQ);
  k_poolstat<<<512,256,0,stream>>>(y,statS,statQ,incg,incb,kw,a1w,attS,attQ,hpool,wpart);
  k_cot2<<<512,256,0,stream>>>(y,statS,statQ,incg,incb,attS,attQ,ag,ab,kw,a1w,a2w,
                               hpool,wpart,pjw,pjg,pjb,chw,chb,cww,cwb,esum,ahB,awB);
  k_mix_fuse<<<512,256,0,stream>>>(y,statS,statQ,incg,incb,attS,attQ,ag,ab,kw,vw,a1w,a2w,
                                   ahB,awB,esum,alpha,beta,fw,fuw,F,fusS,fusQ);
  k_gstat<<<4096,256,0,stream>>>((const float4*)F,fusS,fusQ,fg,fb,gsum);
  k_expand<<<dim3(128,8),256,0,stream>>>((const float4*)F,fusS,fusQ,fg,fb,gw,gsum,ew,(vf4*)out);
}

// Round 10
// 368.004 us; speedup vs baseline: 1.6160x; 1.0805x over previous
//
#include <hip/hip_runtime.h>
#include <math.h>

#define NB 8
#define CIN 512
#define CM 32
#define MG 8
#define HH 128
#define WW 128
#define HWSZ (HH*WW)
#define EPSF 1e-5f
#define COT_ITAU 1.25f   // 1/0.8
#define LAM 0.7f
#define GFLOOR 0.05f

typedef float vf4 __attribute__((ext_vector_type(4)));

__device__ __forceinline__ float wsum(float v){
#pragma unroll
  for (int o = 32; o; o >>= 1) v += __shfl_xor(v, o, 64);
  return v;
}

// transpose compress weights [32][512] -> [512][32]
__global__ void k_tw(const float* __restrict__ w, float* __restrict__ wT){
  int i = blockIdx.x*256 + threadIdx.x;
  if (i < CM*CIN){
    int c = i >> 9, k = i & (CIN-1);
    wT[k*CM + c] = w[i];
  }
}

// compress conv v3: float4 positions, split-K=4 channel groups (blockIdx.y).
// grid (128, 4) x 256 thr. Each thread: 4 positions, 128 input channels, 32 out.
__global__ __launch_bounds__(256) void k_compress4(
    const float* __restrict__ x, const float* __restrict__ wT,
    float* __restrict__ part)           // [4][NB*CM*HWSZ] partials
{
  int tid = threadIdx.x;
  int bt  = blockIdx.x;          // 0..127: b = bt>>4, tile = bt&15
  int kg  = blockIdx.y;          // 0..3
  int b   = bt >> 4;
  int p4  = (bt & 15)*256 + tid; // float4 index in plane (0..4095)
  const vf4* xb = (const vf4*)(x + ((size_t)b*CIN + kg*128)*HWSZ) + p4;
  const float* wh = wT + kg*128*CM;
  vf4 acc[CM];
#pragma unroll
  for (int c=0;c<CM;c++) acc[c] = (vf4)(0.f);
  vf4 xv[4], xn[4];
#pragma unroll
  for (int u=0;u<4;u++) xv[u] = __builtin_nontemporal_load(xb + (size_t)u*(HWSZ/4));
  for (int i=0;i<128;i+=4){
    if (i+4<128){
#pragma unroll
      for (int u=0;u<4;u++) xn[u] = __builtin_nontemporal_load(xb + (size_t)(i+4+u)*(HWSZ/4));
    }
#pragma unroll
    for (int u=0;u<4;u++){
      const float* wr = wh + (i+u)*CM;   // uniform -> scalar loads
#pragma unroll
      for (int c=0;c<CM;c++){
        float wv = wr[c];
        acc[c].x = fmaf(wv, xv[u].x, acc[c].x);
        acc[c].y = fmaf(wv, xv[u].y, acc[c].y);
        acc[c].z = fmaf(wv, xv[u].z, acc[c].z);
        acc[c].w = fmaf(wv, xv[u].w, acc[c].w);
      }
    }
#pragma unroll
    for (int u=0;u<4;u++) xv[u]=xn[u];
  }
  vf4* ob = (vf4*)(part + (size_t)kg*NB*CM*HWSZ) + (size_t)(b*CM)*(HWSZ/4) + p4;
#pragma unroll
  for (int c=0;c<CM;c++) ob[(size_t)c*(HWSZ/4)] = acc[c];
}

// combine 4 partials -> y, plus per-(b,c) sum/sumsq stats
__global__ __launch_bounds__(256) void k_comb4(
    const vf4* __restrict__ p0, const vf4* __restrict__ p1,
    const vf4* __restrict__ p2, const vf4* __restrict__ p3,
    vf4* __restrict__ y, float* __restrict__ s1, float* __restrict__ s2)
{
  int idx = blockIdx.x*256 + threadIdx.x;       // over NB*CM*HWSZ/4
  vf4 a = p0[idx] + p1[idx] + p2[idx] + p3[idx];
  y[idx] = a;
  int bc = idx >> 12;                           // 4096 float4 per (b,c)
  float s = a.x+a.y+a.z+a.w;
  float q = a.x*a.x+a.y*a.y+a.z*a.z+a.w*a.w;
  s = wsum(s); q = wsum(q);
  if ((threadIdx.x&63)==0){ atomicAdd(&s1[bc],s); atomicAdd(&s2[bc],q); }
}

// att_pre stats + BOTH pools in one y-pass (r9-validated).
__global__ __launch_bounds__(256) void k_poolstat(
  const float* __restrict__ y,
  const float* __restrict__ s1i, const float* __restrict__ s2i,
  const float* __restrict__ incg, const float* __restrict__ incb,
  const float* __restrict__ kw, const float* __restrict__ a1w,
  float* __restrict__ s1, float* __restrict__ s2,
  float* __restrict__ hpool, float* __restrict__ wpart)
{
  __shared__ float nA[CM], nB[CM];
  __shared__ float sh[CM][128];
  int tid=threadIdx.x;
  int blk=blockIdx.x;
  int b = blk >> 6;
  int p = ((blk&63)<<8)+tid;
  if (tid<CM){
    float mu  = s1i[b*CM+tid]*(1.f/HWSZ);
    float var = fmaf(-mu,mu, s2i[b*CM+tid]*(1.f/HWSZ));
    float a   = rsqrtf(var+EPSF)*incg[tid];
    nA[tid]=a; nB[tid]=incb[tid]-mu*a;
  }
  __syncthreads();
  size_t base = ((size_t)b*CM)*HWSZ + p;
  float xc[CM], k1[CM], at[CM];
#pragma unroll
  for (int c=0;c<CM;c++)
    xc[c] = fmaxf(0.f, fmaf(y[base+(size_t)c*HWSZ], nA[c], nB[c]));
  // wpool partial: row0 + row1 per column
  if (tid>=128){
#pragma unroll
    for (int c=0;c<CM;c++) sh[c][tid-128]=xc[c];
  }
  __syncthreads();
  if (tid<128){
    float* wp = wpart + (size_t)blk*(CM*WW) + tid;
#pragma unroll
    for (int c=0;c<CM;c++) wp[c*WW] = xc[c] + sh[c][tid];
  }
  // hpool: per-wave row sums
  {
    int hrow = p >> 7;
    float ms=0.f;
#pragma unroll
    for (int c=0;c<CM;c++){
      float s=wsum(xc[c]);
      if ((tid&63)==c) ms=s;
    }
    int lane=tid&63;
    if (lane<CM) atomicAdd(&hpool[(b*CM+lane)*HH+hrow], ms*(1.f/WW));
  }
  // att_pre stats
#pragma unroll
  for (int gI=0;gI<4;gI++)
#pragma unroll
    for (int o=0;o<MG;o++){
      float sk=0.f;
#pragma unroll
      for (int i=0;i<MG;i++) sk = fmaf(kw[gI*64+o*8+i], xc[gI*MG+i], sk);
      k1[gI*MG+o]=sk;
    }
#pragma unroll
  for (int gI=0;gI<4;gI++)
#pragma unroll
    for (int o=0;o<MG;o++){
      float s=0.f;
#pragma unroll
      for (int i=0;i<16;i++){
        float inp = (gI<2) ? k1[gI*16+i] : xc[(gI-2)*16+i];
        s = fmaf(a1w[gI*128+o*16+i], inp, s);
      }
      at[gI*MG+o]=s;
    }
  float ms=0.f,mq=0.f;
#pragma unroll
  for (int c=0;c<CM;c++){
    float s=wsum(at[c]); float q=wsum(at[c]*at[c]);
    if ((tid&63)==c){ms=s;mq=q;}
  }
  int lane=tid&63;
  if (lane<CM){ atomicAdd(&s1[b*CM+lane],ms); atomicAdd(&s2[b*CM+lane],mq); }
}

// reduce wpart -> wpool with full parallelism (256 blocks x 128 threads)
__global__ void k_wred(const float* __restrict__ wpart, float* __restrict__ wpool){
  int bc = blockIdx.x;             // b*CM + c
  int w  = threadIdx.x;            // 0..127
  int b  = bc >> 5;
  int c  = bc & 31;
  const float* src = wpart + (size_t)(b*64)*(CM*WW) + c*WW + w;
  float s=0.f;
#pragma unroll 8
  for (int k=0;k<64;k++) s += src[(size_t)k*(CM*WW)];
  wpool[bc*WW + w] = s*(1.0f/HH);
}

// softmax denominator (recomputes att from y); blocks 0..15 also run coord MLP
__global__ __launch_bounds__(256) void k_cot2(
  const float* __restrict__ y,
  const float* __restrict__ s1i, const float* __restrict__ s2i,
  const float* __restrict__ incg, const float* __restrict__ incb,
  const float* __restrict__ s1a, const float* __restrict__ s2a,
  const float* __restrict__ ag, const float* __restrict__ ab,
  const float* __restrict__ kw, const float* __restrict__ a1w, const float* __restrict__ a2w,
  const float* __restrict__ hpool, const float* __restrict__ wpool,
  const float* __restrict__ pjw, const float* __restrict__ pjg, const float* __restrict__ pjb,
  const float* __restrict__ chw, const float* __restrict__ chb,
  const float* __restrict__ cww, const float* __restrict__ cwb,
  float* __restrict__ es, float* __restrict__ ah, float* __restrict__ aw)
{
  __shared__ float T[CM][HH+1];
  __shared__ float sa[CM], sb[CM], smx[CM], ssc[CM];
  __shared__ float nA[CM], nB[CM], tA[CM], tB[CM];
  int tid=threadIdx.x;
  int blk=blockIdx.x;
  int b = blk >> 6;
  int p = ((blk&63)<<8)+tid;
  if (tid<CM){
    float mu  = s1i[b*CM+tid]*(1.f/HWSZ);
    float var = fmaf(-mu,mu, s2i[b*CM+tid]*(1.f/HWSZ));
    float a   = rsqrtf(var+EPSF)*incg[tid];
    nA[tid]=a; nB[tid]=incb[tid]-mu*a;
    float mu2  = s1a[b*CM+tid]*(1.f/HWSZ);
    float var2 = fmaf(-mu2,mu2, s2a[b*CM+tid]*(1.f/HWSZ));
    float a2   = rsqrtf(var2+EPSF)*ag[tid];
    tA[tid]=a2; tB[tid]=ab[tid]-mu2*a2;
  }
  __syncthreads();
  size_t base = ((size_t)b*CM)*HWSZ + p;
  float xc[CM], k1[CM], at[CM], l[CM];
#pragma unroll
  for (int c=0;c<CM;c++)
    xc[c] = fmaxf(0.f, fmaf(y[base+(size_t)c*HWSZ], nA[c], nB[c]));
#pragma unroll
  for (int gI=0;gI<4;gI++)
#pragma unroll
    for (int o=0;o<MG;o++){
      float sk=0.f;
#pragma unroll
      for (int i=0;i<MG;i++) sk = fmaf(kw[gI*64+o*8+i], xc[gI*MG+i], sk);
      k1[gI*MG+o]=sk;
    }
#pragma unroll
  for (int gI=0;gI<4;gI++)
#pragma unroll
    for (int o=0;o<MG;o++){
      float s=0.f;
#pragma unroll
      for (int i=0;i<16;i++){
        float inp = (gI<2) ? k1[gI*16+i] : xc[(gI-2)*16+i];
        s = fmaf(a1w[gI*128+o*16+i], inp, s);
      }
      at[gI*MG+o]=s;
    }
#pragma unroll
  for (int c=0;c<CM;c++)
    at[c] = fmaxf(0.f, fmaf(at[c], tA[c], tB[c]));
#pragma unroll
  for (int gI=0;gI<4;gI++)
#pragma unroll
    for (int o=0;o<MG;o++){
      float s=0.f;
#pragma unroll
      for (int i=0;i<MG;i++) s = fmaf(a2w[gI*64+o*8+i], at[gI*8+i], s);
      l[gI*MG+o]=s;
    }
  float ms=0.f;
#pragma unroll
  for (int c=0;c<CM;c++){
    float s = wsum(__expf(l[c]*COT_ITAU));
    if ((tid&63)==c) ms=s;
  }
  int lane=tid&63;
  if (lane<CM) atomicAdd(&es[b*CM+lane], ms);

  // ---- coord MLP (blocks 0..15): direct pool reads (r7-validated) ----
  if (blk < 2*NB){
    int bb = blk>>1, path = blk&1;
    const float* pool = path ? wpool : hpool;
    const float* w2   = path ? cww : chw;
    const float* b2   = path ? cwb : chb;
    float* outp       = path ? aw  : ah;
    float z[CM];
    if (tid<HH){
      float in[CM];
#pragma unroll
      for (int c=0;c<CM;c++) in[c] = pool[(bb*CM+c)*HH + tid];
#pragma unroll
      for (int gI=0;gI<4;gI++)
#pragma unroll
        for (int o=0;o<MG;o++){
          float s=0.f;
#pragma unroll
          for (int i=0;i<MG;i++) s = fmaf(pjw[gI*64+o*8+i], in[gI*8+i], s);
          T[gI*8+o][tid] = s;
        }
    }
    __syncthreads();
    if (tid < CM){
      float s=0.f, q=0.f;
      for (int k=0;k<HH;k++){ float t=T[tid][k]; s+=t; q+=t*t; }
      float mu = s*(1.0f/HH);
      float var = q*(1.0f/HH) - mu*mu;
      float a = rsqrtf(var+EPSF)*pjg[tid];
      sa[tid]=a; sb[tid]=pjb[tid]-mu*a;
    }
    __syncthreads();
    if (tid<HH){
      float sil[CM];
#pragma unroll
      for (int c=0;c<CM;c++){
        float val = fmaf(T[c][tid], sa[c], sb[c]);
        sil[c] = val/(1.f+__expf(-val));
      }
#pragma unroll
      for (int gI=0;gI<4;gI++)
#pragma unroll
        for (int o=0;o<MG;o++){
          float s=b2[gI*8+o];
#pragma unroll
          for (int i=0;i<MG;i++) s = fmaf(w2[gI*64+o*8+i], sil[gI*8+i], s);
          z[gI*8+o]=s;
        }
    }
    __syncthreads();
    if (tid<HH){
#pragma unroll
      for (int c=0;c<CM;c++) T[c][tid]=z[c];
    }
    __syncthreads();
    if (tid < CM){
      float mx=-1e30f;
      for (int k=0;k<HH;k++) mx = fmaxf(mx, T[tid][k]);
      float s=0.f;
      for (int k=0;k<HH;k++) s += __expf(T[tid][k]-mx);
      smx[tid]=mx; ssc[tid]=(float)HH/s;
    }
    __syncthreads();
    if (tid<HH){
#pragma unroll
      for (int c=0;c<CM;c++)
        outp[(bb*CM+c)*HH + tid] = __expf(T[c][tid]-smx[c])*ssc[c];
    }
  }
}

// recompute k1/v/att/logits; mix + cot_fuse + coord combine + fusion (+ fus stats)
__global__ __launch_bounds__(256) void k_mix_fuse(
  const float* __restrict__ y,
  const float* __restrict__ s1i, const float* __restrict__ s2i,
  const float* __restrict__ incg, const float* __restrict__ incb,
  const float* __restrict__ s1a, const float* __restrict__ s2a,
  const float* __restrict__ ag, const float* __restrict__ ab,
  const float* __restrict__ kw, const float* __restrict__ vw,
  const float* __restrict__ a1w, const float* __restrict__ a2w,
  const float* __restrict__ ah, const float* __restrict__ awp, const float* __restrict__ es,
  const float* __restrict__ alpha, const float* __restrict__ beta,
  const float* __restrict__ fw, const float* __restrict__ fuw,
  float* __restrict__ fpo, float* __restrict__ s1, float* __restrict__ s2)
{
  __shared__ float nA[CM], nB[CM], tA[CM], tB[CM];
  int tid=threadIdx.x;
  int b = blockIdx.x>>6;
  int p = ((blockIdx.x&63)<<8)+tid;
  int h = p >> 7, w = p & (WW-1);
  if (tid<CM){
    float mu  = s1i[b*CM+tid]*(1.f/HWSZ);
    float var = fmaf(-mu,mu, s2i[b*CM+tid]*(1.f/HWSZ));
    float a   = rsqrtf(var+EPSF)*incg[tid];
    nA[tid]=a; nB[tid]=incb[tid]-mu*a;
    float mu2  = s1a[b*CM+tid]*(1.f/HWSZ);
    float var2 = fmaf(-mu2,mu2, s2a[b*CM+tid]*(1.f/HWSZ));
    float a2   = rsqrtf(var2+EPSF)*ag[tid];
    tA[tid]=a2; tB[tid]=ab[tid]-mu2*a2;
  }
  __syncthreads();
  size_t base = ((size_t)b*CM)*HWSZ + p;
  float al=alpha[0], be=beta[0];
  float xc[CM], k1[CM], at[CM], l[CM], t[CM];
#pragma unroll
  for (int c=0;c<CM;c++)
    xc[c] = fmaxf(0.f, fmaf(y[base+(size_t)c*HWSZ], nA[c], nB[c]));
#pragma unroll
  for (int gI=0;gI<4;gI++)
#pragma unroll
    for (int o=0;o<MG;o++){
      float sk=0.f;
#pragma unroll
      for (int i=0;i<MG;i++) sk = fmaf(kw[gI*64+o*8+i], xc[gI*MG+i], sk);
      k1[gI*MG+o]=sk;
    }
#pragma unroll
  for (int gI=0;gI<4;gI++)
#pragma unroll
    for (int o=0;o<MG;o++){
      float s=0.f;
#pragma unroll
      for (int i=0;i<16;i++){
        float inp = (gI<2) ? k1[gI*16+i] : xc[(gI-2)*16+i];
        s = fmaf(a1w[gI*128+o*16+i], inp, s);
      }
      at[gI*MG+o]=s;
    }
#pragma unroll
  for (int c=0;c<CM;c++)
    at[c] = fmaxf(0.f, fmaf(at[c], tA[c], tB[c]));
#pragma unroll
  for (int gI=0;gI<4;gI++)
#pragma unroll
    for (int o=0;o<MG;o++){
      float s=0.f;
#pragma unroll
      for (int i=0;i<MG;i++) s = fmaf(a2w[gI*64+o*8+i], at[gI*8+i], s);
      l[gI*MG+o]=s;
    }
#pragma unroll
  for (int gI=0;gI<4;gI++)
#pragma unroll
    for (int o=0;o<MG;o++){
      float sv=0.f;
#pragma unroll
      for (int i=0;i<MG;i++) sv = fmaf(vw[gI*64+o*8+i], xc[gI*MG+i], sv);
      int c = gI*MG+o;
      float lgv = l[c];
      float sm = __expf(lgv*COT_ITAU) * (16384.f/es[b*CM+c]);
      float sg = 1.f/(1.f+__expf(-lgv));
      float mix = (1.f-LAM)*sg + LAM*sm;
      t[c] = fmaf(mix, sv, k1[c]);
    }
  float co[CM];
#pragma unroll
  for (int c=0;c<CM;c++){
    float wl = al*ah[(b*CM+c)*HH + h] + be*awp[(b*CM+c)*WW + w];
    co[c] = xc[c] * wl;   // kappa = 1
  }
  float cot[CM];
#pragma unroll
  for (int o=0;o<CM;o++){
    float s=0.f;
#pragma unroll
    for (int i=0;i<CM;i++) s = fmaf(fw[o*CM+i], t[i], s);
    cot[o]=s;
  }
  float ms=0.f, mq=0.f;
#pragma unroll
  for (int o=0;o<CM;o++){
    float s=0.f;
#pragma unroll
    for (int i=0;i<CM;i++) s = fmaf(fuw[o*64+i], co[i], s);
#pragma unroll
    for (int i=0;i<CM;i++) s = fmaf(fuw[o*64+32+i], cot[i], s);
    fpo[base+(size_t)o*HWSZ]=s;
    float ss = wsum(s); float qq = wsum(s*s);
    if ((tid&63)==o){ ms=ss; mq=qq; }
  }
  int lane=tid&63;
  if (lane<CM){ atomicAdd(&s1[b*CM+lane],ms); atomicAdd(&s2[b*CM+lane],mq); }
}

// gate statistics: sum of relu(norm(fused_pre)) per (b,c), inline affine
__global__ __launch_bounds__(256) void k_gstat(const float4* __restrict__ fp,
  const float* __restrict__ s1f, const float* __restrict__ s2f,
  const float* __restrict__ fg, const float* __restrict__ fb,
  float* __restrict__ gsum)
{
  int idx = blockIdx.x*256+threadIdx.x;  // NB*CM*HWSZ/4
  int bc = idx >> 12;
  int c = bc & (CM-1);
  float mu  = s1f[bc]*(1.f/HWSZ);
  float var = fmaf(-mu,mu, s2f[bc]*(1.f/HWSZ));
  float a   = rsqrtf(var+EPSF)*fg[c];
  float bb  = fb[c]-mu*a;
  float4 tv = fp[idx];
  float s = fmaxf(0.f,fmaf(tv.x,a,bb))+fmaxf(0.f,fmaf(tv.y,a,bb))
          + fmaxf(0.f,fmaf(tv.z,a,bb))+fmaxf(0.f,fmaf(tv.w,a,bb));
  s = wsum(s);
  if ((threadIdx.x&63)==0) atomicAdd(&gsum[bc], s);
}

// expand conv 32->512: inline fus affine + inline gate; nt stores
__global__ __launch_bounds__(256) void k_expand(const float4* __restrict__ fp4,
  const float* __restrict__ s1f, const float* __restrict__ s2f,
  const float* __restrict__ fg, const float* __restrict__ fb,
  const float* __restrict__ gw, const float* __restrict__ gsum,
  const float* __restrict__ ew, vf4* __restrict__ out4)
{
  __shared__ float fA[CM], fB[CM];
  int tid = threadIdx.x;
  int b = blockIdx.x >> 4;
  int tile = blockIdx.x & 15;
  int p4 = tile*256 + tid;            // float4 idx within batch plane (0..4095)
  int og = blockIdx.y * 64;
  if (tid<CM){
    float mu  = s1f[b*CM+tid]*(1.f/HWSZ);
    float var = fmaf(-mu,mu, s2f[b*CM+tid]*(1.f/HWSZ));
    float a   = rsqrtf(var+EPSF)*fg[tid];
    fA[tid]=a; fB[tid]=fb[tid]-mu*a;
  }
  float s=0.f;
#pragma unroll
  for (int c=0;c<CM;c++) s = fmaf(gw[c], gsum[b*CM+c], s);
  s *= (1.0f/HWSZ);
  float gt = 1.f/(1.f+__expf(-s));
  float sc = gt*(1.f-GFLOOR)+GFLOOR;
  __syncthreads();
  float4 f[CM];
  const float4* fbp = fp4 + ((size_t)b*CM)*(HWSZ/4) + p4;
#pragma unroll
  for (int c=0;c<CM;c++){
    float4 t = fbp[(size_t)c*(HWSZ/4)];
    float a=fA[c], bb=fB[c];
    f[c].x = fmaxf(0.f, fmaf(t.x,a,bb))*sc;
    f[c].y = fmaxf(0.f, fmaf(t.y,a,bb))*sc;
    f[c].z = fmaxf(0.f, fmaf(t.z,a,bb))*sc;
    f[c].w = fmaxf(0.f, fmaf(t.w,a,bb))*sc;
  }
  vf4* ob = out4 + ((size_t)b*CIN + og)*(HWSZ/4) + p4;
  for (int j=0;j<64;j++){
    const float* wr = ew + (og+j)*CM;   // uniform -> scalar loads
    vf4 acc = (vf4)(0.f);
#pragma unroll
    for (int c=0;c<CM;c++){
      float wv = wr[c];
      acc.x = fmaf(wv, f[c].x, acc.x);
      acc.y = fmaf(wv, f[c].y, acc.y);
      acc.z = fmaf(wv, f[c].z, acc.z);
      acc.w = fmaf(wv, f[c].w, acc.w);
    }
    __builtin_nontemporal_store(acc, &ob[(size_t)j*(HWSZ/4)]);
  }
}

extern "C" void kernel_launch(void* const* d_in, const int* in_sizes, int n_in,
                              void* d_out, int out_size, void* d_ws, size_t ws_size,
                              hipStream_t stream)
{
  const float* x    = (const float*)d_in[0];
  const float* cw   = (const float*)d_in[1];
  const float* incg = (const float*)d_in[2];
  const float* incb = (const float*)d_in[3];
  const float* pjw  = (const float*)d_in[4];
  const float* pjg  = (const float*)d_in[5];
  const float* pjb  = (const float*)d_in[6];
  const float* chw  = (const float*)d_in[7];
  const float* chb  = (const float*)d_in[8];
  const float* cww  = (const float*)d_in[9];
  const float* cwb  = (const float*)d_in[10];
  const float* alpha= (const float*)d_in[11];
  const float* beta = (const float*)d_in[12];
  const float* kw   = (const float*)d_in[13];
  const float* vw   = (const float*)d_in[14];
  const float* a1w  = (const float*)d_in[15];
  const float* ag   = (const float*)d_in[16];
  const float* ab   = (const float*)d_in[17];
  const float* a2w  = (const float*)d_in[18];
  const float* fw   = (const float*)d_in[19];
  const float* fuw  = (const float*)d_in[20];
  const float* fg   = (const float*)d_in[21];
  const float* fb   = (const float*)d_in[22];
  const float* gw   = (const float*)d_in[23];
  const float* ew   = (const float*)d_in[24];
  float* out = (float*)d_out;

  float* ws = (float*)d_ws;
  const size_t BIG = (size_t)NB*CM*HWSZ;  // 4,194,304 floats (16 MiB)
  float* part = ws;                 // 4 x BIG partials; part0 doubles as F
  float* F    = ws;                 // fused_pre (aliases part0; parts dead by then)
  float* y    = ws + 4*BIG;
  float* sm   = ws + 5*BIG;
  float* acc   = sm;  sm += 2048;            // zeroed accumulators
  float* statS = acc,      *statQ = acc+256;
  float* attS  = acc+512,  *attQ  = acc+768;
  float* esum  = acc+1024;
  float* fusS  = acc+1280, *fusQ  = acc+1536;
  float* gsum  = acc+1792;
  float* hpool = sm;  sm += NB*CM*HH;        // zeroed (atomic-accumulated)
  float* wT    = sm;  sm += CM*CIN;
  float* wpart = sm;  sm += (size_t)512*CM*WW;  // 8 MiB partials
  float* wpool = sm;  sm += NB*CM*WW;
  float* ahB   = sm;  sm += NB*CM*HH;
  float* awB   = sm;  sm += NB*CM*WW;

  hipMemsetAsync(acc, 0, (2048 + NB*CM*HH)*sizeof(float), stream);
  k_tw<<<64,256,0,stream>>>(cw, wT);
  k_compress4<<<dim3(128,4),256,0,stream>>>(x, wT, part);
  k_comb4<<<4096,256,0,stream>>>((const vf4*)part,(const vf4*)(part+BIG),
                                 (const vf4*)(part+2*BIG),(const vf4*)(part+3*BIG),
                                 (vf4*)y, statS, statQ);
  k_poolstat<<<512,256,0,stream>>>(y,statS,statQ,incg,incb,kw,a1w,attS,attQ,hpool,wpart);
  k_wred<<<NB*CM,128,0,stream>>>(wpart, wpool);
  k_cot2<<<512,256,0,stream>>>(y,statS,statQ,incg,incb,attS,attQ,ag,ab,kw,a1w,a2w,
                               hpool,wpool,pjw,pjg,pjb,chw,chb,cww,cwb,esum,ahB,awB);
  k_mix_fuse<<<512,256,0,stream>>>(y,statS,statQ,incg,incb,attS,attQ,ag,ab,kw,vw,a1w,a2w,
                                   ahB,awB,esum,alpha,beta,fw,fuw,F,fusS,fusQ);
  k_gstat<<<4096,256,0,stream>>>((const float4*)F,fusS,fusQ,fg,fb,gsum);
  k_expand<<<dim3(128,8),256,0,stream>>>((const float4*)F,fusS,fusQ,fg,fb,gw,gsum,ew,(vf4*)out);
}